// Round 5
// baseline (180.758 us; speedup 1.0000x reference)
//
#include <hip/hip_runtime.h>

// AttentionBlock: B=8, T=2048, D=K=V=512. Inputs fp32, OUTPUT fp32.
// out = x + einsum('bts,bsv->btv', softmax_over_t(mask(q@k^T))/sqrt(512), v)
// softmax is over axis=1 (query axis t) per key-column s — column softmax.

typedef __attribute__((ext_vector_type(4))) float f32x4;
typedef __attribute__((ext_vector_type(8))) short s16x8;
typedef __attribute__((ext_vector_type(4))) short s16x4;

#define SENT   -1e30f
#define SQRTK  22.627416997969522f   // sqrt(512)

__device__ __forceinline__ short f2bf(float f) {
    union { float f; unsigned int i; } c; c.f = f;
    unsigned int x = c.i;
    return (short)((x + 0x7fffu + ((x >> 16) & 1u)) >> 16);
}

// ---------------------------------------------------------------------------
// fp32 -> bf16 cast, 4 elems/thread, vectorized.
// ---------------------------------------------------------------------------
__global__ __launch_bounds__(256) void k_cast(
    const float* __restrict__ in, unsigned short* __restrict__ out, int n4)
{
    int i = blockIdx.x * 256 + threadIdx.x;
    if (i >= n4) return;
    f32x4 v = *(const f32x4*)(in + (size_t)i * 4);
    s16x4 o;
#pragma unroll
    for (int j = 0; j < 4; ++j) o[j] = f2bf(v[j]);
    *(s16x4*)(out + (size_t)i * 4) = o;
}

// Merged cast of the three 512x512 weights (one launch instead of three).
__global__ __launch_bounds__(256) void k_castw(
    const float* __restrict__ a, const float* __restrict__ b, const float* __restrict__ c,
    unsigned short* __restrict__ oa, unsigned short* __restrict__ ob, unsigned short* __restrict__ oc)
{
    int i = blockIdx.x * 256 + threadIdx.x;   // 0..196607 float4-groups
    const float* src; unsigned short* dst; int j;
    if (i < 65536)       { src = a; dst = oa; j = i; }
    else if (i < 131072) { src = b; dst = ob; j = i - 65536; }
    else                 { src = c; dst = oc; j = i - 131072; }
    f32x4 v = *(const f32x4*)(src + (size_t)j * 4);
    s16x4 o;
#pragma unroll
    for (int jj = 0; jj < 4; ++jj) o[jj] = f2bf(v[jj]);
    *(s16x4*)(dst + (size_t)j * 4) = o;
}

// ---------------------------------------------------------------------------
// Generic bf16 GEMM: C[M][N] = A[M][512] . Bt[N][512]^T + bias(fp32), bf16 out.
// 128x128 tile, BK=32, 4 waves (2x2), double-buffered LDS, reg-staged loads.
// ---------------------------------------------------------------------------
__global__ __launch_bounds__(256) void k_proj(
    const unsigned short* __restrict__ A,    // [M][512] bf16
    const unsigned short* __restrict__ Bt,   // [N][512] bf16
    const float* __restrict__ bias,          // [M] if per_row else [N], fp32
    unsigned short* __restrict__ C,          // [M][N] bf16
    int N, int bias_per_row)
{
    __shared__ short la[2][128][32];
    __shared__ short lb[2][128][32];
    const int tid  = threadIdx.x;
    const int wave = tid >> 6, lane = tid & 63;
    const int wr = (wave >> 1) * 64, wc = (wave & 1) * 64;
    const int m0 = blockIdx.x * 128, n0 = blockIdx.y * 128;
    const int srow = tid >> 2, scol = (tid & 3) * 8;
    const int frl = lane & 15, kb = (lane >> 4) * 8, rg4 = (lane >> 4) * 4;
    f32x4 acc[4][4] = {};
    s16x8 ra[2], rb[2];

#define PROJ_LOAD(K0) \
    { _Pragma("unroll") for (int p = 0; p < 2; ++p) { \
        int r = srow + p * 64; \
        ra[p] = *(const s16x8*)(A  + (size_t)(m0 + r) * 512 + (K0) + scol); \
        rb[p] = *(const s16x8*)(Bt + (size_t)(n0 + r) * 512 + (K0) + scol); } }
#define PROJ_WRITE(BUF) \
    { _Pragma("unroll") for (int p = 0; p < 2; ++p) { \
        int r = srow + p * 64; \
        *(s16x8*)(&la[BUF][r][scol]) = ra[p]; \
        *(s16x8*)(&lb[BUF][r][scol]) = rb[p]; } }

    PROJ_LOAD(0);
    PROJ_WRITE(0);
    __syncthreads();
    for (int ks = 0; ks < 16; ++ks) {
        const int cur = ks & 1;
        if (ks < 15) PROJ_LOAD((ks + 1) * 32);
        s16x8 af[4], bfr[4];
#pragma unroll
        for (int i = 0; i < 4; ++i) af[i]  = *(const s16x8*)(&la[cur][wr + i * 16 + frl][kb]);
#pragma unroll
        for (int i = 0; i < 4; ++i) bfr[i] = *(const s16x8*)(&lb[cur][wc + i * 16 + frl][kb]);
#pragma unroll
        for (int mi = 0; mi < 4; ++mi)
#pragma unroll
            for (int ni = 0; ni < 4; ++ni)
                acc[mi][ni] = __builtin_amdgcn_mfma_f32_16x16x32_bf16(af[mi], bfr[ni], acc[mi][ni], 0, 0, 0);
        if (ks < 15) PROJ_WRITE(cur ^ 1);
        __syncthreads();
    }
#pragma unroll
    for (int mi = 0; mi < 4; ++mi)
#pragma unroll
        for (int ni = 0; ni < 4; ++ni) {
            int col = n0 + wc + ni * 16 + frl;
#pragma unroll
            for (int r = 0; r < 4; ++r) {
                int row = m0 + wr + mi * 16 + rg4 + r;
                float bv = bias[bias_per_row ? row : col];
                C[(size_t)row * N + col] = f2bf(acc[mi][ni][r] + bv);
            }
        }
#undef PROJ_LOAD
#undef PROJ_WRITE
}

// ---------------------------------------------------------------------------
// L[b][t][s] = Q[b,t,:].K[b,s,:] (fp32), masked (s>t) -> SENT, PLUS fused
// per-column (m, Z) partials per 128-row chunk. 1-D grid over the 136 valid
// triangular tiles x 8 batches (uniform work). Double-buffered.
// ---------------------------------------------------------------------------
__global__ __launch_bounds__(256) void k_logits(
    const unsigned short* __restrict__ Q,   // [B][2048][512]
    const unsigned short* __restrict__ Km,  // [B][2048][512]
    float* __restrict__ L,                  // [B][2048][2048]
    float* __restrict__ pm, float* __restrict__ pz)  // [B*16][2048]
{
    const int n = blockIdx.x;
    const int b = n & 7;
    const int p = n >> 3;                       // 0..135 triangular index
    int tt = (int)((sqrtf(8.f * p + 1.f) - 1.f) * 0.5f);
    while ((tt + 1) * (tt + 2) / 2 <= p) ++tt;
    while (tt * (tt + 1) / 2 > p) --tt;
    const int st = p - tt * (tt + 1) / 2;       // st <= tt
    const int t0 = tt * 128, s0 = st * 128;

    const unsigned short* A  = Q  + (size_t)b * 2048 * 512;
    const unsigned short* Bt = Km + (size_t)b * 2048 * 512;
    float* Lb = L + (size_t)b * 2048 * 2048;

    __shared__ short la[2][128][32];
    __shared__ short lb[2][128][32];
    __shared__ float sm[2][128];
    __shared__ float sz[2][128];
    const int tid  = threadIdx.x;
    const int wave = tid >> 6, lane = tid & 63;
    const int wr = (wave >> 1) * 64, wc = (wave & 1) * 64;
    const int srow = tid >> 2, scol = (tid & 3) * 8;
    const int frl = lane & 15, kb = (lane >> 4) * 8, rg4 = (lane >> 4) * 4;
    f32x4 acc[4][4] = {};
    s16x8 ra[2], rb[2];

#define LG_LOAD(K0) \
    { _Pragma("unroll") for (int q = 0; q < 2; ++q) { \
        int r = srow + q * 64; \
        ra[q] = *(const s16x8*)(A  + (size_t)(t0 + r) * 512 + (K0) + scol); \
        rb[q] = *(const s16x8*)(Bt + (size_t)(s0 + r) * 512 + (K0) + scol); } }
#define LG_WRITE(BUF) \
    { _Pragma("unroll") for (int q = 0; q < 2; ++q) { \
        int r = srow + q * 64; \
        *(s16x8*)(&la[BUF][r][scol]) = ra[q]; \
        *(s16x8*)(&lb[BUF][r][scol]) = rb[q]; } }

    LG_LOAD(0);
    LG_WRITE(0);
    __syncthreads();
    for (int ks = 0; ks < 16; ++ks) {
        const int cur = ks & 1;
        if (ks < 15) LG_LOAD((ks + 1) * 32);
        s16x8 af[4], bfr[4];
#pragma unroll
        for (int i = 0; i < 4; ++i) af[i]  = *(const s16x8*)(&la[cur][wr + i * 16 + frl][kb]);
#pragma unroll
        for (int i = 0; i < 4; ++i) bfr[i] = *(const s16x8*)(&lb[cur][wc + i * 16 + frl][kb]);
#pragma unroll
        for (int mi = 0; mi < 4; ++mi)
#pragma unroll
            for (int ni = 0; ni < 4; ++ni)
                acc[mi][ni] = __builtin_amdgcn_mfma_f32_16x16x32_bf16(af[mi], bfr[ni], acc[mi][ni], 0, 0, 0);
        if (ks < 15) LG_WRITE(cur ^ 1);
        __syncthreads();
    }
#undef LG_LOAD
#undef LG_WRITE

    // Epilogue: mask + store L + per-column (max, sumexp) over this tile's 128 rows.
    float cm[4], cz[4];
#pragma unroll
    for (int ni = 0; ni < 4; ++ni) {
        const int colg = s0 + wc + ni * 16 + frl;
        float xs[4][4];
        float ml = SENT;
#pragma unroll
        for (int mi = 0; mi < 4; ++mi)
#pragma unroll
            for (int r = 0; r < 4; ++r) {
                int row = t0 + wr + mi * 16 + rg4 + r;
                float x = (colg <= row) ? acc[mi][ni][r] : SENT;
                Lb[(size_t)row * 2048 + colg] = x;
                xs[mi][r] = x;
                ml = fmaxf(ml, x);
            }
        ml = fmaxf(ml, __shfl_xor(ml, 16));
        ml = fmaxf(ml, __shfl_xor(ml, 32));   // max over the 4 row-groups
        float zl = 0.f;
#pragma unroll
        for (int mi = 0; mi < 4; ++mi)
#pragma unroll
            for (int r = 0; r < 4; ++r)
                zl += __expf(xs[mi][r] - ml);
        zl += __shfl_xor(zl, 16);
        zl += __shfl_xor(zl, 32);
        cm[ni] = ml; cz[ni] = zl;
    }
    if (lane < 16) {
#pragma unroll
        for (int ni = 0; ni < 4; ++ni) {
            sm[wr >> 6][wc + ni * 16 + lane] = cm[ni];
            sz[wr >> 6][wc + ni * 16 + lane] = cz[ni];
        }
    }
    __syncthreads();
    if (tid < 128) {
        float M0 = sm[0][tid], M1 = sm[1][tid];
        float M = fmaxf(M0, M1);
        float Z = sz[0][tid] * __expf(M0 - M) + sz[1][tid] * __expf(M1 - M);
        int o = (b * 16 + tt) * 2048 + s0 + tid;
        pm[o] = M; pz[o] = Z;
    }
}

// Combine 16 chunk partials -> column max + rcp = 1/(Z*sqrt(512)).
// Chunks tc < s>>7 were never written (fully-masked region) -> skipped.
__global__ __launch_bounds__(256) void k_stats2(
    const float* __restrict__ pm, const float* __restrict__ pz,
    float* __restrict__ mcol, float* __restrict__ rcp)
{
    const int i = blockIdx.x * 256 + threadIdx.x;  // b*2048 + s
    const int b = i >> 11, s = i & 2047;
    const int tc0 = s >> 7;
    float M = SENT;
    for (int tc = tc0; tc < 16; ++tc) M = fmaxf(M, pm[(b * 16 + tc) * 2048 + s]);
    float Z = 0.f;
    for (int tc = tc0; tc < 16; ++tc) {
        int o = (b * 16 + tc) * 2048 + s;
        Z += pz[o] * __expf(pm[o] - M);
    }
    mcol[i] = M;
    rcp[i]  = 1.0f / (Z * SQRTK);
}

// ---------------------------------------------------------------------------
// out[b,t,v] = x[b,t,v] + sum_s exp(L[t,s]-m_s)*rcp_s * Vt[v, b*2048+s]
// Fine-grained for occupancy: block = 64 t-rows x 128 v-cols, grid 1024
// (4 blocks/CU, 16 waves/CU). LDS 24KB/block. Complementary t-tile mapping:
// the 4 co-resident blocks {t5, t5+8, 31-t5, 23-t5} sum to 132 s-steps on
// every CU (exact balance). Double-buffered, reg-staged, fused exp.
// ---------------------------------------------------------------------------
__global__ __launch_bounds__(256, 4) void k_out(
    const float* __restrict__ L,           // [B][2048][2048]
    const float* __restrict__ mcol,        // [B*2048]
    const float* __restrict__ rcp,         // [B*2048]
    const unsigned short* __restrict__ Vt, // [512][B*2048] bf16
    const float* __restrict__ X,           // [B][2048][512] fp32
    float* __restrict__ Y)                 // [B][2048][512] fp32
{
    __shared__ short la[2][64][32];    // P'[t][s]  (4KB each)
    __shared__ short lb[2][128][32];   // Vt[v][s]  (8KB each)
    const int n  = blockIdx.x;
    const int lo = n & 511, hi = n >> 9;
    const int b = lo & 7, vh = (lo >> 3) & 3, t5 = lo >> 5;   // t5: 0..15
    const int tt = hi ? (31 - t5) : t5;                       // 0..31
    const int t0 = tt * 64, v0 = vh * 128;
    const float* Lb = L + (size_t)b * 2048 * 2048;
    const float* mb = mcol + b * 2048;
    const float* rb = rcp  + b * 2048;
    const int tid  = threadIdx.x;
    const int wave = tid >> 6, lane = tid & 63;
    const int wc = wave * 32;                 // wave's v sub-chunk
    const int frl = lane & 15, kb = (lane >> 4) * 8, rg4 = (lane >> 4) * 4;

    // staging coords
    const int tr  = tid >> 2;        // A row (0..63)
    const int sc  = (tid & 3) * 8;   // A col group (8 floats)
    const int vr  = tid >> 1;        // B row (0..127)
    const int scB = (tid & 1) * 16;  // B col group (16 shorts)

    f32x4 acc[4][2] = {};
    f32x4 lA0, lA1, m40, m41, r40, r41;
    s16x8 vb0, vb1;
    const int nst = (tt + 1) * 2;    // 32-wide s-steps (causal)

#define OUT_LOAD(IS) \
    { int s0_ = (IS) * 32; \
      const float* lp = Lb + (size_t)(t0 + tr) * 2048 + s0_ + sc; \
      lA0 = *(const f32x4*)(lp); lA1 = *(const f32x4*)(lp + 4); \
      m40 = *(const f32x4*)(mb + s0_ + sc); m41 = *(const f32x4*)(mb + s0_ + sc + 4); \
      r40 = *(const f32x4*)(rb + s0_ + sc); r41 = *(const f32x4*)(rb + s0_ + sc + 4); \
      const unsigned short* vp = Vt + (size_t)(v0 + vr) * 16384 + b * 2048 + s0_ + scB; \
      vb0 = *(const s16x8*)(vp); vb1 = *(const s16x8*)(vp + 8); }
#define OUT_WRITE(BUF) \
    { s16x8 o_; \
      _Pragma("unroll") for (int j = 0; j < 4; ++j) { \
          o_[j]     = f2bf(__expf(lA0[j] - m40[j]) * r40[j]); \
          o_[j + 4] = f2bf(__expf(lA1[j] - m41[j]) * r41[j]); } \
      *(s16x8*)(&la[BUF][tr][sc]) = o_; \
      *(s16x8*)(&lb[BUF][vr][scB]) = vb0; \
      *(s16x8*)(&lb[BUF][vr][scB + 8]) = vb1; }

    OUT_LOAD(0);
    OUT_WRITE(0);
    __syncthreads();
    for (int is = 0; is < nst; ++is) {
        const int cur = is & 1;
        if (is + 1 < nst) OUT_LOAD(is + 1);
        s16x8 af[4], bfr[2];
#pragma unroll
        for (int i = 0; i < 4; ++i) af[i]  = *(const s16x8*)(&la[cur][i * 16 + frl][kb]);
#pragma unroll
        for (int i = 0; i < 2; ++i) bfr[i] = *(const s16x8*)(&lb[cur][wc + i * 16 + frl][kb]);
#pragma unroll
        for (int mi = 0; mi < 4; ++mi)
#pragma unroll
            for (int ni = 0; ni < 2; ++ni)
                acc[mi][ni] = __builtin_amdgcn_mfma_f32_16x16x32_bf16(af[mi], bfr[ni], acc[mi][ni], 0, 0, 0);
        if (is + 1 < nst) OUT_WRITE(cur ^ 1);
        __syncthreads();
    }
#undef OUT_LOAD
#undef OUT_WRITE

#pragma unroll
    for (int mi = 0; mi < 4; ++mi)
#pragma unroll
        for (int ni = 0; ni < 2; ++ni) {
            int col = v0 + wc + ni * 16 + frl;
#pragma unroll
            for (int r = 0; r < 4; ++r) {
                int row = t0 + mi * 16 + rg4 + r;
                size_t o = ((size_t)b * 2048 + row) * 512 + col;
                Y[o] = acc[mi][ni][r] + X[o];
            }
        }
}

extern "C" void kernel_launch(void* const* d_in, const int* in_sizes, int n_in,
                              void* d_out, int out_size, void* d_ws, size_t ws_size,
                              hipStream_t stream) {
    const float* Xf  = (const float*)d_in[0];
    const float* Wkf = (const float*)d_in[1];
    const float* bkf = (const float*)d_in[2];
    const float* Wqf = (const float*)d_in[3];
    const float* bqf = (const float*)d_in[4];
    const float* Wvf = (const float*)d_in[5];
    const float* bvf = (const float*)d_in[6];
    float* Y = (float*)d_out;
    char* ws = (char*)d_ws;

    // workspace layout (bytes); total ~193.5 MB
    // Xb is dead after the projections; pm/pz/mc/rc overlay it (written by
    // k_logits/k_stats2 which run strictly after all k_proj).
    unsigned short* Xb  = (unsigned short*)(ws);                    // 16 MB  [16384][512]
    float*          pm  = (float*)(ws);                             // 1 MB   [8*16][2048] (overlays Xb)
    float*          pz  = (float*)(ws + 1048576);                   // 1 MB
    float*          mc  = (float*)(ws + 2097152);                   // 64 KB
    float*          rc  = (float*)(ws + 2162688);                   // 64 KB
    unsigned short* Qb  = (unsigned short*)(ws + 16777216);         // 16 MB  [16384][512]
    unsigned short* Kb  = (unsigned short*)(ws + 33554432);         // 16 MB  [16384][512]
    unsigned short* Vt  = (unsigned short*)(ws + 50331648);         // 16 MB  [512][16384]
    unsigned short* Wkb = (unsigned short*)(ws + 67108864);         // 512 KB [512][512]
    unsigned short* Wqb = (unsigned short*)(ws + 67633152);         // 512 KB
    unsigned short* Wvb = (unsigned short*)(ws + 68157440);         // 512 KB
    float*          Lg  = (float*)(ws + 68681728);                  // 128 MB [8][2048][2048]

    dim3 blk(256);
    // fp32 -> bf16 casts
    k_cast<<<dim3(8192), blk, 0, stream>>>(Xf, Xb, 2097152);
    k_castw<<<dim3(768), blk, 0, stream>>>(Wkf, Wqf, Wvf, Wkb, Wqb, Wvb);
    // Q = X.Wq^T + bq ; K = X.Wk^T + bk  (M=16384, N=512)
    k_proj<<<dim3(128, 4), blk, 0, stream>>>(Xb, Wqb, bqf, Qb, 512, 0);
    k_proj<<<dim3(128, 4), blk, 0, stream>>>(Xb, Wkb, bkf, Kb, 512, 0);
    // Vt = Wv.X^T + bv (per-row bias) -> values transposed [512][16384]
    k_proj<<<dim3(4, 128), blk, 0, stream>>>(Wvb, Xb, bvf, Vt, 16384, 1);
    // logits + fused column-stats partials (1088 uniform triangular blocks)
    k_logits<<<dim3(1088), blk, 0, stream>>>(Qb, Kb, Lg, pm, pz);
    // combine partials -> per-column max + 1/(Z*sqrt(512))
    k_stats2<<<dim3(64), blk, 0, stream>>>(pm, pz, mc, rc);
    // P.V + residual (fine-grained, 4 blocks/CU, exact balance)
    k_out<<<dim3(1024), blk, 0, stream>>>(Lg, mc, rc, Vt, Xf, Y);
}